// Round 7
// baseline (2525.712 us; speedup 1.0000x reference)
//
#include <hip/hip_runtime.h>
#include <cstdint>
#include <cstddef>

typedef unsigned short u16;
typedef unsigned int u32;
typedef unsigned long long u64;
typedef __attribute__((ext_vector_type(8))) short bf16x8;  // 8 x bf16 (4 VGPRs)
typedef __attribute__((ext_vector_type(4))) float f32x4;
typedef __attribute__((ext_vector_type(4))) unsigned short u16x4;

#define DEV __device__ __forceinline__

DEV float bf2f(u16 h) { union { unsigned int u; float f; } x; x.u = ((unsigned int)h) << 16; return x.f; }
DEV u16 f2bf(float f) {
    union { float f; unsigned int u; } x; x.f = f;
    unsigned int u = x.u;
    return (u16)((u + 0x7fffu + ((u >> 16) & 1u)) >> 16);   // RNE
}
// fast gate math: __expf + v_rcp_f32; rel err ~1e-6 << bf16 weight rounding
DEV float fsig(float x)  { float e = __expf(-x);      return __builtin_amdgcn_rcpf(1.0f + e); }
DEV float ftanh(float x) { float e = __expf(2.0f * x); return 1.0f - 2.0f * __builtin_amdgcn_rcpf(e + 1.0f); }
DEV f32x4 mfma16(bf16x8 a, bf16x8 b, f32x4 c) {
    return __builtin_amdgcn_mfma_f32_16x16x32_bf16(a, b, c, 0, 0, 0);
}

// B=256, T=256, E=128, H=128 (per direction), H2=256. ALL tensors fp32.
//
// r15 (round 7): stages 2+3 become ONE PERSISTENT launch (512 blocks = exact
// 2/CU residency): 256 chain blocks (same-XCD mapping) + 256 GEMM workers.
// Removes the per-slot fixed costs the counters exposed: 17x 32MB Whh VGPR
// refetch (critical-path at slot start), cb round-trips (c stays in regs all
// 256 steps), 18 launch gaps + pipeline refills. Chunk handoff (CH=16, same
// double buffers) via agent-scope flag counters: release fetch_add by
// producers (publishes bulk data cross-XCD; previously the launch boundary
// did this), relaxed-spin + acquire RMW by consumers (no L2-inv churn while
// polling). Dependency DAG: A_c<-S2_{c-2}; B_cc<-S2_cc,S3_{cc-2};
// S2_c<-A_c,B_{c-2}; S3_c<-B_c; worker order A_c then B_{c-1} -- acyclic.
// h-exchange tags run t=1..256 continuously (r0-proven protocol, unchanged).

union __align__(16) SMemU {
    struct { u16 As[2][64][40]; u16 Bs[256][40]; } g;   // 10240 + 20480 = 30720 B
    struct { u16 Al[2][16][136]; } r1;                  // recur1 h dbuf (8704 B)
    struct { u16 Al[16][264]; } r2;                     // recur2 h stage (8448 B)
};

// flag indices (u32 array, memset to 0 per call)
enum { G2D = 0, G3D = 32, C2F = 64, C3F = 96 };

template<int SLP>
DEV void wflag(u32* p, u32 tgt) {
    if (threadIdx.x == 0) {
        while (__hip_atomic_load(p, __ATOMIC_RELAXED, __HIP_MEMORY_SCOPE_AGENT) < tgt)
            __builtin_amdgcn_s_sleep(SLP);
        __hip_atomic_fetch_add(p, 0u, __ATOMIC_ACQUIRE, __HIP_MEMORY_SCOPE_AGENT);
    }
    __syncthreads();
}
DEV void sflag(u32* p, u32 v) {
    __syncthreads();   // all threads' stores drained (vmcnt0) before publish
    if (threadIdx.x == 0)
        __hip_atomic_fetch_add(p, v, __ATOMIC_RELEASE, __HIP_MEMORY_SCOPE_AGENT);
}

// ---------------------------------------------------------------------------
// prep: fp32 -> bf16 conversion for 4 arrays in one launch
// ---------------------------------------------------------------------------
__global__ __launch_bounds__(256) void prep_w4_kernel(
    const float* __restrict__ a0, u16* __restrict__ o0, int c0,
    const float* __restrict__ a1, u16* __restrict__ o1, int c1,
    const float* __restrict__ a2, u16* __restrict__ o2, int c2,
    const float* __restrict__ a3, u16* __restrict__ o3)
{
    int blk = blockIdx.x;
    const float* a; u16* o; int off;
    if (blk < c0)                { a = a0; o = o0; off = blk; }
    else if (blk < c0 + c1)      { a = a1; o = o1; off = blk - c0; }
    else if (blk < c0 + c1 + c2) { a = a2; o = o2; off = blk - c0 - c1; }
    else                         { a = a3; o = o3; off = blk - c0 - c1 - c2; }
    int i = off * 256 + threadIdx.x;
    o[i] = f2bf(a[i]);
}

// ---------------------------------------------------------------------------
// prep: ln1 over X1 rows, store bf16 hi/lo planes IN PLACE over the row.
// ---------------------------------------------------------------------------
__global__ __launch_bounds__(256) void prep_x1_kernel(
    float* __restrict__ X, const float* __restrict__ gw, const float* __restrict__ bw)
{
    int row  = blockIdx.x * 4 + (threadIdx.x >> 6);
    int lane = threadIdx.x & 63;
    float* xr = X + (size_t)row * 256;
    f32x4 v = *(const f32x4*)(xr + lane * 4);
    float s = v[0] + v[1] + v[2] + v[3];
    #pragma unroll
    for (int mm = 1; mm < 64; mm <<= 1) s += __shfl_xor(s, mm, 64);
    float mu = s * (1.0f / 256.0f);
    f32x4 e = v - mu;
    float q = e[0]*e[0] + e[1]*e[1] + e[2]*e[2] + e[3]*e[3];
    #pragma unroll
    for (int mm = 1; mm < 64; mm <<= 1) q += __shfl_xor(q, mm, 64);
    float rs = rsqrtf(q * (1.0f / 256.0f) + 1e-5f);
    int c0 = lane * 4;
    u16x4 hv, lv;
    #pragma unroll
    for (int i = 0; i < 4; ++i) {
        float o = e[i] * rs * gw[c0 + i] + bw[c0 + i];
        u16 hh = f2bf(o);
        hv[i] = hh;
        lv[i] = f2bf(o - bf2f(hh));
    }
    u16* H = (u16*)xr;
    *(u16x4*)(H + lane * 4)       = hv;
    *(u16x4*)(H + 256 + lane * 4) = lv;
}

// ---------------------------------------------------------------------------
// xg GEMM body, first (bi) layer. A = embed fp32 (split on the fly), W bf16.
// ---------------------------------------------------------------------------
DEV void xg_fr_body(SMemU* smu, int bx, int by, int nby,
    const float* __restrict__ embed,
    const u16* __restrict__ Wf16, const float* __restrict__ bf_,
    const u16* __restrict__ Wr16, const float* __restrict__ br_,
    float* __restrict__ xgf, float* __restrict__ xgr, int t0f, int t0r)
{
    auto& As = smu->g.As[0];
    auto& Bs = smu->g.Bs;
    int tid = threadIdx.x;
    int half = nby >> 1;
    bool isR = by >= half;
    int m0 = (by - (isR ? half : 0)) * 64;
    const u16* W      = isR ? Wr16 : Wf16;
    const float* bias = isR ? br_ : bf_;
    float* out        = isR ? xgr : xgf;
    int tbase         = isR ? t0r : t0f;
    int n0 = bx * 64;

    int r  = tid >> 2;
    int kc = (tid & 3) * 8;
    int m  = m0 + r;
    int tl = m >> 8, bb = m & 255;
    const float* arow = embed + ((size_t)(bb * 256 + (tbase + tl)) * 128);
    const u16* brow = W + ((size_t)(n0 + r) * 128);

    f32x4 acc[4];
    #pragma unroll
    for (int i = 0; i < 4; ++i) acc[i] = (f32x4){0.f, 0.f, 0.f, 0.f};
    int lane = tid & 63, w = tid >> 6;
    int fr_ = lane & 15, kb0 = (lane >> 4) * 8;

    for (int kt = 0; kt < 8; ++kt) {
        int sc = (kt & 3) * 32 + kc;
        bool lo = kt >= 4;
        f32x4 va = *(const f32x4*)(arow + sc);
        f32x4 vb = *(const f32x4*)(arow + sc + 4);
        bf16x8 wv = *(const bf16x8*)(brow + sc);
        bf16x8 hv;
        #pragma unroll
        for (int i = 0; i < 8; ++i) {
            float v = (i < 4) ? va[i] : vb[i - 4];
            u16 hi = f2bf(v);
            hv[i] = (short)(lo ? f2bf(v - bf2f(hi)) : hi);
        }
        *(bf16x8*)&As[r][kc] = hv;
        *(bf16x8*)&Bs[r][kc] = wv;
        __syncthreads();
        bf16x8 bfrg = *(const bf16x8*)&Bs[w * 16 + fr_][kb0];
        #pragma unroll
        for (int mt = 0; mt < 4; ++mt) {
            bf16x8 afrg = *(const bf16x8*)&As[mt * 16 + fr_][kb0];
            acc[mt] = mfma16(afrg, bfrg, acc[mt]);
        }
        __syncthreads();
    }
    int col = n0 + w * 16 + fr_;
    float bvv = bias[col];
    int rq = (lane >> 4) * 4;
    #pragma unroll
    for (int mt = 0; mt < 4; ++mt)
        #pragma unroll
        for (int rr = 0; rr < 4; ++rr) {
            int mrow = m0 + mt * 16 + rq + rr;
            out[(size_t)mrow * 512 + col] = acc[mt][rr] + bvv;
        }
}

// ---------------------------------------------------------------------------
// LEAN layer-2 xg GEMM, 64x256 tile (swizzled Bs; B staged once; hi+lo A).
// ---------------------------------------------------------------------------
DEV void xg_l16_body(SMemU* smu, int bx, int by,
    const u16* __restrict__ X1p, const u16* __restrict__ Wp,
    const float* __restrict__ bias, float* __restrict__ out, int t0)
{
    auto& As = smu->g.As;       // [2][64][40]
    auto& Bs = smu->g.Bs;       // [256][40]
    int tid = threadIdx.x;
    int m0 = by * 64, n0 = bx * 256;
    int rA = tid >> 2, kcA = (tid & 3) * 8;
    int m  = m0 + rA;
    int tl = m >> 8, bb = m & 255;
    const u16* arow = X1p + ((size_t)((t0 + tl) * 256 + bb)) * 512;  // H then L plane
    const u16* brow = Wp + ((size_t)(n0 + tid)) * 256;
    int swB = (tid >> 3) & 3;

    f32x4 acc[4][4];
    #pragma unroll
    for (int cs = 0; cs < 4; ++cs)
        #pragma unroll
        for (int i = 0; i < 4; ++i) acc[cs][i] = (f32x4){0.f, 0.f, 0.f, 0.f};
    int lane = tid & 63, w = tid >> 6;
    int fr_ = lane & 15, quad = lane >> 4, kb0 = quad * 8;

    for (int kt = 0; kt < 8; ++kt) {
        int sc = kt * 32;
        bf16x8 hvH = *(const bf16x8*)(arow + sc + kcA);
        bf16x8 hvL = *(const bf16x8*)(arow + 256 + sc + kcA);
        bf16x8 wv0 = *(const bf16x8*)(brow + sc);
        bf16x8 wv1 = *(const bf16x8*)(brow + sc + 8);
        bf16x8 wv2 = *(const bf16x8*)(brow + sc + 16);
        bf16x8 wv3 = *(const bf16x8*)(brow + sc + 24);
        *(bf16x8*)&As[0][rA][kcA] = hvH;
        *(bf16x8*)&As[1][rA][kcA] = hvL;
        *(bf16x8*)&Bs[tid][(0 ^ swB) * 8] = wv0;
        *(bf16x8*)&Bs[tid][(1 ^ swB) * 8] = wv1;
        *(bf16x8*)&Bs[tid][(2 ^ swB) * 8] = wv2;
        *(bf16x8*)&Bs[tid][(3 ^ swB) * 8] = wv3;
        __syncthreads();
        bf16x8 bfrg[4];
        #pragma unroll
        for (int cs = 0; cs < 4; ++cs) {
            int Br = cs * 64 + w * 16 + fr_;
            int g  = quad ^ ((Br >> 3) & 3);
            bfrg[cs] = *(const bf16x8*)&Bs[Br][g * 8];
        }
        #pragma unroll
        for (int h = 0; h < 2; ++h)
            #pragma unroll
            for (int mt = 0; mt < 4; ++mt) {
                bf16x8 afrg = *(const bf16x8*)&As[h][mt * 16 + fr_][kb0];
                #pragma unroll
                for (int cs = 0; cs < 4; ++cs)
                    acc[cs][mt] = mfma16(afrg, bfrg[cs], acc[cs][mt]);
            }
        __syncthreads();
    }
    int rq = (lane >> 4) * 4;
    #pragma unroll
    for (int cs = 0; cs < 4; ++cs) {
        int col = n0 + cs * 64 + w * 16 + fr_;
        float bvv = bias[col];
        #pragma unroll
        for (int mt = 0; mt < 4; ++mt)
            #pragma unroll
            for (int rr = 0; rr < 4; ++rr) {
                int mrow = m0 + mt * 16 + rq + rr;
                out[(size_t)mrow * 1024 + col] = acc[cs][mt][rr] + bvv;
            }
    }
}

// ---------------------------------------------------------------------------
// layer-3 xg GEMM, 64x128 tile, double-A: A = ln2( R + (H+L of ln1X1) ).
// ---------------------------------------------------------------------------
DEV void xg_ln3_body(SMemU* smu, int bx, int by,
    const u16* __restrict__ X1p, const float* __restrict__ Rc,
    const float* __restrict__ l2g, const float* __restrict__ l2b,
    const u16* __restrict__ Wp, const float* __restrict__ bias,
    float* __restrict__ out, int t0)
{
    auto& As = smu->g.As;       // [2][64][40]
    auto& Bs = smu->g.Bs;       // rows [0,128)
    int tid = threadIdx.x;
    int m0 = by * 64, n0 = bx * 128;
    int rA = tid >> 2, kcA = (tid & 3) * 8;
    int rB = tid >> 1, cB = tid & 1;
    int m  = m0 + rA;
    int tl = m >> 8, bb = m & 255;
    const u16* a1 = X1p + ((size_t)((t0 + tl) * 256 + bb)) * 512;
    const float* a2 = Rc + ((size_t)(tl * 256 + bb)) * 256;
    const u16* brow = Wp + ((size_t)(n0 + rB)) * 256;
    int swB = (rB >> 3) & 3;

    float xc[8][8];
    float s = 0.f;
    #pragma unroll
    for (int q = 0; q < 8; ++q) {
        int sc = q * 32 + kcA;
        bf16x8 hx = *(const bf16x8*)(a1 + sc);
        bf16x8 lx = *(const bf16x8*)(a1 + 256 + sc);
        f32x4 u2 = *(const f32x4*)(a2 + sc);
        f32x4 v2 = *(const f32x4*)(a2 + sc + 4);
        #pragma unroll
        for (int i = 0; i < 8; ++i) {
            float rv = (i < 4) ? u2[i] : v2[i - 4];
            xc[q][i] = bf2f((u16)hx[i]) + bf2f((u16)lx[i]) + rv;
            s += xc[q][i];
        }
    }
    s += __shfl_xor(s, 1); s += __shfl_xor(s, 2);
    float mu = s * (1.0f / 256.0f);
    float q2 = 0.f;
    #pragma unroll
    for (int q = 0; q < 8; ++q)
        #pragma unroll
        for (int i = 0; i < 8; ++i) { float e = xc[q][i] - mu; q2 += e * e; }
    q2 += __shfl_xor(q2, 1); q2 += __shfl_xor(q2, 2);
    float rs = rsqrtf(q2 * (1.0f / 256.0f) + 1e-5f);
    #pragma unroll
    for (int q = 0; q < 8; ++q) {
        int sc = q * 32 + kcA;
        f32x4 g1 = *(const f32x4*)(l2g + sc);
        f32x4 g2v = *(const f32x4*)(l2g + sc + 4);
        f32x4 h1 = *(const f32x4*)(l2b + sc);
        f32x4 h2 = *(const f32x4*)(l2b + sc + 4);
        #pragma unroll
        for (int i = 0; i < 4; ++i) {
            xc[q][i]     = (xc[q][i]     - mu) * rs * g1[i]  + h1[i];
            xc[q][4 + i] = (xc[q][4 + i] - mu) * rs * g2v[i] + h2[i];
        }
    }

    f32x4 acc[2][4];
    #pragma unroll
    for (int cs = 0; cs < 2; ++cs)
        #pragma unroll
        for (int i = 0; i < 4; ++i) acc[cs][i] = (f32x4){0.f, 0.f, 0.f, 0.f};
    int lane = tid & 63, w = tid >> 6;
    int fr_ = lane & 15, quad = lane >> 4, kb0 = quad * 8;

    #pragma unroll        // xc must be statically indexed (no scratch)
    for (int kt = 0; kt < 8; ++kt) {
        int sc = kt * 32;
        bf16x8 wv0 = *(const bf16x8*)(brow + sc + cB * 16);
        bf16x8 wv1 = *(const bf16x8*)(brow + sc + cB * 16 + 8);
        bf16x8 hvH, hvL;
        #pragma unroll
        for (int i = 0; i < 8; ++i) {
            float v = xc[kt][i];
            u16 hi = f2bf(v);
            hvH[i] = (short)hi;
            hvL[i] = (short)f2bf(v - bf2f(hi));
        }
        *(bf16x8*)&As[0][rA][kcA] = hvH;
        *(bf16x8*)&As[1][rA][kcA] = hvL;
        *(bf16x8*)&Bs[rB][((2 * cB) ^ swB) * 8]     = wv0;
        *(bf16x8*)&Bs[rB][((2 * cB + 1) ^ swB) * 8] = wv1;
        __syncthreads();
        bf16x8 bfrg[2];
        #pragma unroll
        for (int cs = 0; cs < 2; ++cs) {
            int Br = cs * 64 + w * 16 + fr_;
            int g  = quad ^ ((Br >> 3) & 3);
            bfrg[cs] = *(const bf16x8*)&Bs[Br][g * 8];
        }
        #pragma unroll
        for (int h = 0; h < 2; ++h)
            #pragma unroll
            for (int mt = 0; mt < 4; ++mt) {
                bf16x8 afrg = *(const bf16x8*)&As[h][mt * 16 + fr_][kb0];
                #pragma unroll
                for (int cs = 0; cs < 2; ++cs)
                    acc[cs][mt] = mfma16(afrg, bfrg[cs], acc[cs][mt]);
            }
        __syncthreads();
    }
    int rq = (lane >> 4) * 4;
    #pragma unroll
    for (int cs = 0; cs < 2; ++cs) {
        int col = n0 + cs * 64 + w * 16 + fr_;
        float bvv = bias[col];
        #pragma unroll
        for (int mt = 0; mt < 4; ++mt)
            #pragma unroll
            for (int rr = 0; rr < 4; ++rr) {
                int mrow = m0 + mt * 16 + rq + rr;
                out[(size_t)mrow * 1024 + col] = acc[cs][mt][rr] + bvv;
            }
    }
}

// ---------------------------------------------------------------------------
// Stage-1 recurrence body (unchanged from r6).
// ---------------------------------------------------------------------------
DEV void recur1_body(SMemU* smu, int bid,
    const float* __restrict__ xgf, const float* __restrict__ xgr,
    const u16* __restrict__ whf16, const u16* __restrict__ whr16,
    float* __restrict__ cbf, float* __restrict__ cbr,
    float* __restrict__ hpf, float* __restrict__ hpr,
    float* __restrict__ xout, int s0, int s1)
{
    __builtin_amdgcn_s_setprio(1);
    constexpr int K = 128, N4 = 512;
    auto& Al = smu->r1.Al;

    int tid = threadIdx.x, lane = tid & 63, w = tid >> 6;
    int fr_ = lane & 15, quad = lane >> 4, kb0 = quad * 8;
    int dir = bid >> 5, gidx = bid & 31;
    const float* xg  = dir ? xgr  : xgf;
    const u16* whh16 = dir ? whr16 : whf16;
    float* cb = dir ? cbr : cbf;
    float* hp = dir ? hpr : hpf;
    int coloff = dir ? 128 : 0;

    bf16x8 bf[4][2][4];
    #pragma unroll
    for (int g = 0; g < 4; ++g)
        #pragma unroll
        for (int u = 0; u < 2; ++u) {
            const u16* src = whh16 + (size_t)(g * K + w * 32 + u * 16 + fr_) * K;
            #pragma unroll
            for (int kt = 0; kt < 4; ++kt)
                bf[g][u][kt] = *(const bf16x8*)(src + kt * 32 + kb0);
        }

    int uq = quad >> 1, qrow = quad & 1;
    int colw = w * 32 + uq * 16 + fr_;        // 0..127
    int b0 = gidx * 8;
    float c[4];
    #pragma unroll
    for (int rr = 0; rr < 4; ++rr)
        c[rr] = (s0 > 0) ? cb[(size_t)(b0 + qrow * 4 + rr) * K + colw] : 0.f;

    if (s0 > 0) {
        for (int idx = tid; idx < 8 * K; idx += 256) {
            int sa = idx >> 7, k = idx & 127;
            float v = hp[(size_t)(b0 + sa) * K + k];
            u16 hh = f2bf(v);
            Al[s0 & 1][sa][k] = hh;
            Al[s0 & 1][8 + sa][k] = f2bf(v - bf2f(hh));
        }
    }
    __syncthreads();

    float xv[4][4];
    {
        int xrow = dir ? (s1 - 1 - s0) : 0;
        #pragma unroll
        for (int rr = 0; rr < 4; ++rr) {
            const float* xp = xg + ((size_t)(xrow * 256 + b0 + qrow * 4 + rr)) * N4 + colw;
            #pragma unroll
            for (int g = 0; g < 4; ++g) xv[rr][g] = xp[g * K];
        }
    }

    for (int t = s0; t < s1; ++t) {
        float xn[4][4];
        {
            int tn = (t + 1 < s1) ? (t + 1) : t;
            int xrow = dir ? (s1 - 1 - tn) : (tn - s0);
            #pragma unroll
            for (int rr = 0; rr < 4; ++rr) {
                const float* xp = xg + ((size_t)(xrow * 256 + b0 + qrow * 4 + rr)) * N4 + colw;
                #pragma unroll
                for (int g = 0; g < 4; ++g) xn[rr][g] = xp[g * K];
            }
        }
        f32x4 acc[4][2];
        if (t > 0) {
            #pragma unroll
            for (int g = 0; g < 4; ++g)
                #pragma unroll
                for (int u = 0; u < 2; ++u) acc[g][u] = (f32x4){0.f, 0.f, 0.f, 0.f};
            #pragma unroll
            for (int kt = 0; kt < 4; ++kt) {
                bf16x8 a = *(const bf16x8*)&Al[t & 1][fr_][kt * 32 + kb0];
                #pragma unroll
                for (int g = 0; g < 4; ++g)
                    #pragma unroll
                    for (int u = 0; u < 2; ++u) acc[g][u] = mfma16(a, bf[g][u][kt], acc[g][u]);
            }
            #pragma unroll
            for (int g = 0; g < 4; ++g)
                #pragma unroll
                for (int u = 0; u < 2; ++u)
                    #pragma unroll
                    for (int rr = 0; rr < 4; ++rr)
                        acc[g][u][rr] += __shfl_xor(acc[g][u][rr], 32);
        }
        int tt = dir ? (255 - t) : t;
        #pragma unroll
        for (int rr = 0; rr < 4; ++rr) {
            int s = qrow * 4 + rr;
            float gg[4];
            #pragma unroll
            for (int g = 0; g < 4; ++g) {
                float pv = (t > 0) ? (uq ? acc[g][1][rr] : acc[g][0][rr]) : 0.f;
                gg[g] = xv[rr][g] + pv;
            }
            c[rr] = fsig(gg[1]) * c[rr] + fsig(gg[0]) * ftanh(gg[2]);
            float h = fsig(gg[3]) * ftanh(c[rr]);
            u16 hh = f2bf(h);
            Al[(t + 1) & 1][s][colw] = hh;
            Al[(t + 1) & 1][8 + s][colw] = f2bf(h - bf2f(hh));
            xout[((size_t)tt * 256 + b0 + s) * 256 + coloff + colw] = h;
            if (t == s1 - 1) hp[(size_t)(b0 + s) * K + colw] = h;
        }
        __syncthreads();
        #pragma unroll
        for (int rr = 0; rr < 4; ++rr)
            #pragma unroll
            for (int g = 0; g < 4; ++g) xv[rr][g] = xn[rr][g];
    }
    #pragma unroll
    for (int rr = 0; rr < 4; ++rr)
        cb[(size_t)(b0 + qrow * 4 + rr) * K + colw] = c[rr];
}

// ---------------------------------------------------------------------------
// PERSISTENT H2 chain (K=256): all 256 steps in one block lifetime.
// c in registers; Whh loaded once; chunk-boundary flag waits; tagged
// agent-atomic h exchange continuous t=1..256.
// OUTY 0: layer-2 chain -> writes R[c&1], signals C2F. waits G2D[c], G3D[c-2].
// OUTY 1: layer-3 chain -> writes y, signals C3F. waits G3D[c].
// ---------------------------------------------------------------------------
template<int OUTY>
DEV void pchain_body(SMemU* smu, int bid,
    const float* __restrict__ xga, const float* __restrict__ xgb,
    const u16* __restrict__ whh16, u64* hb,
    float* __restrict__ r0, float* __restrict__ r1,
    float* __restrict__ yout, const int* __restrict__ lastidx,
    const float* __restrict__ bng, const float* __restrict__ bnb,
    u32* fl)
{
    __builtin_amdgcn_s_setprio(1);
    constexpr int K = 256, MB = 8, N4 = 1024;
    constexpr int CNT = MB * K / 256;
    auto& Al = smu->r2.Al;

    int tid = threadIdx.x, lane = tid & 63, w = tid >> 6;
    int fr_ = lane & 15, quad = lane >> 4, kb0 = quad * 8;
    int group = bid >> 2, cw = bid & 3;
    u64* hbg = hb + (size_t)group * (2 * MB * K);
    int col = cw * 64 + w * 16 + fr_;

    bf16x8 bf[4][8];
    #pragma unroll
    for (int g = 0; g < 4; ++g) {
        const u16* src = whh16 + (size_t)(g * 256 + col) * K;
        #pragma unroll
        for (int kt = 0; kt < 8; ++kt)
            bf[g][kt] = *(const bf16x8*)(src + kt * 32 + kb0);
    }

    int qrow = quad & 1, rhalf = quad >> 1;
    int sp[2], bs[2]; float c[2] = {0.f, 0.f};
    #pragma unroll
    for (int j = 0; j < 2; ++j) {
        sp[j] = qrow * 4 + rhalf * 2 + j;
        bs[j] = group * 8 + sp[j];
    }
    int lastb[2] = { -1, -1 };
    float bngv = 0.f, bnbv = 0.f;
    if (OUTY) {
        bool is64 = (lastidx[1] | lastidx[3] | lastidx[5] | lastidx[7] |
                     lastidx[9] | lastidx[11] | lastidx[13] | lastidx[15]) == 0;
        lastb[0] = is64 ? lastidx[2 * bs[0]] : lastidx[bs[0]];
        lastb[1] = is64 ? lastidx[2 * bs[1]] : lastidx[bs[1]];
        bngv = bng[col] * rsqrtf(1.0f + 1e-5f);
        bnbv = bnb[col];
    }

    for (int ch = 0; ch < 16; ++ch) {
        // chunk-boundary dependency waits (usually already satisfied)
        if (OUTY == 0) {
            wflag<8>(fl + G2D + ch, 256);
            if (ch >= 2) wflag<8>(fl + G3D + ch - 2, 512);
        } else {
            wflag<8>(fl + G3D + ch, 512);
        }
        const float* xg = (ch & 1) ? xgb : xga;
        float* Rw = (ch & 1) ? r1 : r0;

        // first-step xg load for this chunk (no cross-chunk prefetch)
        float xv[2][4];
        #pragma unroll
        for (int j = 0; j < 2; ++j) {
            const float* xp = xg + ((size_t)bs[j]) * N4 + col;
            #pragma unroll
            for (int g = 0; g < 4; ++g) xv[j][g] = xp[g * 256];
        }

        for (int tt = 0; tt < 16; ++tt) {
            int t = ch * 16 + tt;
            float xn[2][4];
            {
                int xr = (tt + 1 < 16) ? (tt + 1) : tt;
                #pragma unroll
                for (int j = 0; j < 2; ++j) {
                    const float* xp = xg + ((size_t)(xr * 256 + bs[j])) * N4 + col;
                    #pragma unroll
                    for (int g = 0; g < 4; ++g) xn[j][g] = xp[g * 256];
                }
            }
            f32x4 acc[4];
            if (t > 0) {
                u64* hsrc = hbg + (size_t)(t & 1) * (MB * K);
                u64 v[CNT];
                #pragma unroll
                for (int i = 0; i < CNT; ++i)
                    v[i] = __hip_atomic_load(hsrc + tid + i * 256,
                                             __ATOMIC_RELAXED, __HIP_MEMORY_SCOPE_AGENT);
                for (;;) {
                    bool ok = true;
                    #pragma unroll
                    for (int i = 0; i < CNT; ++i)
                        if ((unsigned int)(v[i] >> 32) != (unsigned int)t) ok = false;
                    if (ok) break;
                    __builtin_amdgcn_s_sleep(1);
                    #pragma unroll
                    for (int i = 0; i < CNT; ++i)
                        if ((unsigned int)(v[i] >> 32) != (unsigned int)t)
                            v[i] = __hip_atomic_load(hsrc + tid + i * 256,
                                                     __ATOMIC_RELAXED, __HIP_MEMORY_SCOPE_AGENT);
                }
                #pragma unroll
                for (int i = 0; i < CNT; ++i) {
                    unsigned int d = (unsigned int)v[i];
                    Al[i][tid]     = (u16)(d & 0xffffu);
                    Al[8 + i][tid] = (u16)(d >> 16);
                }
                __syncthreads();
                #pragma unroll
                for (int g = 0; g < 4; ++g) acc[g] = (f32x4){0.f, 0.f, 0.f, 0.f};
                #pragma unroll
                for (int kt = 0; kt < 8; ++kt) {
                    bf16x8 a = *(const bf16x8*)&Al[fr_][kt * 32 + kb0];
                    #pragma unroll
                    for (int g = 0; g < 4; ++g) acc[g] = mfma16(a, bf[g][kt], acc[g]);
                }
                #pragma unroll
                for (int g = 0; g < 4; ++g)
                    #pragma unroll
                    for (int rr = 0; rr < 4; ++rr)
                        acc[g][rr] += __shfl_xor(acc[g][rr], 32);
            }
            #pragma unroll
            for (int j = 0; j < 2; ++j) {
                float gg[4];
                #pragma unroll
                for (int g = 0; g < 4; ++g) {
                    float pv = (t > 0) ? (rhalf ? acc[g][2 + j] : acc[g][j]) : 0.f;
                    gg[g] = xv[j][g] + pv;
                }
                c[j] = fsig(gg[1]) * c[j] + fsig(gg[0]) * ftanh(gg[2]);
                float h = fsig(gg[3]) * ftanh(c[j]);
                u16 hh = f2bf(h);
                u16 hl = f2bf(h - bf2f(hh));
                u64 word = (u64)((unsigned int)hh | ((unsigned int)hl << 16))
                         | ((u64)(unsigned int)(t + 1) << 32);
                __hip_atomic_store(hbg + (size_t)((t + 1) & 1) * (MB * K) + (size_t)sp[j] * K + col,
                                   word, __ATOMIC_RELAXED, __HIP_MEMORY_SCOPE_AGENT);
                if (OUTY == 0) {
                    Rw[((size_t)tt * 256 + bs[j]) * 256 + col] = h;
                } else if (t == lastb[j]) {
                    float y = h * bngv + bnbv;
                    y = y > 0.f ? y : 0.f;
                    yout[(size_t)bs[j] * 256 + col] = y;
                }
            }
            __syncthreads();
            #pragma unroll
            for (int j = 0; j < 2; ++j)
                #pragma unroll
                for (int g = 0; g < 4; ++g) xv[j][g] = xn[j][g];
        }
        // publish chunk completion (R data for OUTY=0; buffer-consumed for both)
        sflag(fl + (OUTY ? C3F : C2F) + ch, 1);
    }
}

// ---------------------------------------------------------------------------
// PERSISTENT GEMM worker: per chunk c, 1 layer-2 tile (A_c) then 2 layer-3
// tiles (B_{c-1}), with flag waits. 256 workers.
// ---------------------------------------------------------------------------
DEV void pworker_body(SMemU* smu, int wid,
    const u16* __restrict__ X1p, const u16* __restrict__ w1p,
    const float* __restrict__ b1, float* g2a, float* g2b,
    const float* r0, const float* r1,
    const float* __restrict__ ln2g, const float* __restrict__ ln2b,
    const u16* __restrict__ w2p, const float* __restrict__ b2v,
    float* g3a, float* g3b, u32* fl)
{
    for (int c = 0; c <= 16; ++c) {
        if (c < 16) {
            if (c >= 2) wflag<32>(fl + C2F + c - 2, 128);   // G2[c&1] consumed
            xg_l16_body(smu, wid & 3, wid >> 2, X1p, w1p, b1,
                        (c & 1) ? g2b : g2a, 16 * c);
            sflag(fl + G2D + c, 1);
        }
        if (c >= 1) {
            int cc = c - 1;
            wflag<32>(fl + C2F + cc, 128);                  // R chunk cc ready
            if (cc >= 2) wflag<32>(fl + C3F + cc - 2, 128); // G3[cc&1] consumed
            const float* Rr = (cc & 1) ? r1 : r0;
            float* g3 = (cc & 1) ? g3b : g3a;
            int i0 = wid * 2, i1 = wid * 2 + 1;
            xg_ln3_body(smu, i0 & 7, i0 >> 3, X1p, Rr, ln2g, ln2b, w2p, b2v, g3, 16 * cc);
            xg_ln3_body(smu, i1 & 7, i1 >> 3, X1p, Rr, ln2g, ln2b, w2p, b2v, g3, 16 * cc);
            sflag(fl + G3D + cc, 2);
        }
    }
}

// ---------------------------------------------------------------------------
// Persistent stage-2/3 kernel: 512 blocks (exactly 2/CU -> all resident).
//  [0,256)   chain blocks, same-XCD mapping (verbatim r5/r6)
//  [256,512) GEMM workers
// ---------------------------------------------------------------------------
__global__ __launch_bounds__(256, 2) void persist_kernel(
    float* g2a, float* g2b, float* g3a, float* g3b,
    const u16* __restrict__ wh1, const u16* __restrict__ wh2,
    u64* hb1, u64* hb2, float* r0, float* r1,
    float* __restrict__ yout, const int* __restrict__ lastidx,
    const float* __restrict__ bng, const float* __restrict__ bnb,
    const u16* __restrict__ X1p, const u16* __restrict__ w1p,
    const float* __restrict__ b1,
    const float* __restrict__ ln2g, const float* __restrict__ ln2b,
    const u16* __restrict__ w2p, const float* __restrict__ b2v,
    u32* fl)
{
    __shared__ SMemU sm;
    int b = blockIdx.x;
    if (b < 256) {
        int x = b & 7, k = b >> 3;
        int sub = k & 15;
        int gid = (x * 4 + (sub >> 2)) * 4 + (sub & 3);
        if (k < 16)
            pchain_body<0>(&sm, gid, g2a, g2b, wh1, hb1, r0, r1,
                           nullptr, nullptr, nullptr, nullptr, fl);
        else
            pchain_body<1>(&sm, gid, g3a, g3b, wh2, hb2, nullptr, nullptr,
                           yout, lastidx, bng, bnb, fl);
    } else {
        pworker_body(&sm, b - 256, X1p, w1p, b1, g2a, g2b, r0, r1,
                     ln2g, ln2b, w2p, b2v, g3a, g3b, fl);
    }
}

// ---------------------------------------------------------------------------
// Fused stage-1 launch (unchanged): [0,64) recur1(chunk i-1), rest xg_fr(i).
// ---------------------------------------------------------------------------
__global__ __launch_bounds__(256) void fused1_kernel(
    const float* __restrict__ embed,
    const u16* __restrict__ Wf16, const float* __restrict__ bfb,
    const u16* __restrict__ Wr16, const float* __restrict__ brb,
    float* __restrict__ xgfw, float* __restrict__ xgrw, int t0f, int t0r, int gon,
    const float* __restrict__ xgfr, const float* __restrict__ xgrr,
    const u16* __restrict__ whf16, const u16* __restrict__ whr16,
    float* __restrict__ cbf, float* __restrict__ cbr,
    float* __restrict__ hpf, float* __restrict__ hpr,
    float* __restrict__ X1, int s0, int s1, int ron)
{
    __shared__ SMemU sm;
    int b = blockIdx.x;
    if (b < 64) {
        if (ron)
            recur1_body(&sm, b, xgfr, xgrr, whf16, whr16, cbf, cbr, hpf, hpr, X1, s0, s1);
    } else {
        if (gon) {
            int idx = b - 64;
            xg_fr_body(&sm, idx & 7, idx >> 3, 256, embed, Wf16, bfb, Wr16, brb,
                       xgfw, xgrw, t0f, t0r);
        }
    }
}

// ---------------------------------------------------------------------------
// Launch
// ---------------------------------------------------------------------------
extern "C" void kernel_launch(void* const* d_in, const int* in_sizes, int n_in,
                              void* d_out, int out_size, void* d_ws, size_t ws_size,
                              hipStream_t stream)
{
    (void)in_sizes; (void)n_in; (void)out_size; (void)ws_size;
    const float* embed = (const float*)d_in[0];
    const int* lastidx = (const int*)d_in[1];
    const float* Wih_f = (const float*)d_in[2];
    const float* Whh_f = (const float*)d_in[3];
    const float* b_f   = (const float*)d_in[4];
    const float* Wih_r = (const float*)d_in[5];
    const float* Whh_r = (const float*)d_in[6];
    const float* b_r   = (const float*)d_in[7];
    const float* ln1g  = (const float*)d_in[8];
    const float* ln1b  = (const float*)d_in[9];
    const float* W1ih  = (const float*)d_in[10];
    const float* W1hh  = (const float*)d_in[11];
    const float* b1    = (const float*)d_in[12];
    const float* ln2g  = (const float*)d_in[13];
    const float* ln2b  = (const float*)d_in[14];
    const float* W2ih  = (const float*)d_in[15];
    const float* W2hh  = (const float*)d_in[16];
    const float* b2    = (const float*)d_in[17];
    const float* bng   = (const float*)d_in[18];
    const float* bnb   = (const float*)d_in[19];

    const size_t MiB = 1024 * 1024;
    char* ws = (char*)d_ws;
    float* G2[2] = { (float*)ws,               (float*)(ws + 16 * MiB) };
    float* G3[2] = { (float*)(ws + 32 * MiB),  (float*)(ws + 48 * MiB) };
    float* X1    =   (float*)(ws + 64 * MiB);   // 64 MiB; ln1 bf16 planes in place after prep
    float* R[2]  = { (float*)(ws + 128 * MiB), (float*)(ws + 132 * MiB) };  // 4 MiB each
    char* p = ws + 136 * MiB;
    u64* hb1 = (u64*)p;                         p += 1024 * 1024;
    u64* hb2 = (u64*)p;                         p += 1024 * 1024;
    float* cbf = (float*)p;                     p += 128 * 1024;
    float* cbr = (float*)p;                     p += 128 * 1024;
    float* hpf = (float*)p;                     p += 128 * 1024;
    float* hpr = (float*)p;                     p += 128 * 1024;
    u16* w1p   = (u16*)p;                       p += 512 * 1024;   // W1ih bf16
    u16* w2p   = (u16*)p;                       p += 512 * 1024;   // W2ih bf16
    u16* wfp   = (u16*)p;                       p += 128 * 1024;   // Wih_f bf16
    u16* wrp   = (u16*)p;                       p += 128 * 1024;   // Wih_r bf16
    u16* wh1p  = (u16*)p;                       p += 512 * 1024;   // W1hh bf16
    u16* wh2p  = (u16*)p;                       p += 512 * 1024;   // W2hh bf16
    u16* whfp  = (u16*)p;                       p += 128 * 1024;   // Whh_f bf16
    u16* whrp  = (u16*)p;                       p += 128 * 1024;   // Whh_r bf16
    u32* fl    = (u32*)p;                       // 4 KiB flag region

    const int CH1 = 32, n1 = 8;    // stage-1 chunking

    // reset flags for this invocation (graph-capture-safe async memset)
    hipMemsetAsync(fl, 0, 4096, stream);

    // one-time weight conversions
    prep_w4_kernel<<<2560, 256, 0, stream>>>(
        W1ih, w1p, 1024, W2ih, w2p, 1024, Wih_f, wfp, 256, Wih_r, wrp);
    prep_w4_kernel<<<2560, 256, 0, stream>>>(
        W1hh, wh1p, 1024, W2hh, wh2p, 1024, Whh_f, whfp, 256, Whh_r, whrp);

    // stage 1: bidirectional H=128 LSTM -> X1 (raw concat)
    for (int i = 0; i <= n1; ++i) {
        int gon = (i < n1), ron = (i >= 1);
        float* wf = (i & 1) ? G3[0] : G2[0];
        float* wr = (i & 1) ? G3[1] : G2[1];
        const float* rf = ((i - 1) & 1) ? G3[0] : G2[0];
        const float* rr_ = ((i - 1) & 1) ? G3[1] : G2[1];
        fused1_kernel<<<2112, 256, 0, stream>>>(
            embed, wfp, b_f, wrp, b_r, wf, wr, CH1 * i, 256 - CH1 * (i + 1), gon,
            rf, rr_, whfp, whrp, cbf, cbr, hpf, hpr, X1, CH1 * (i - 1), CH1 * i, ron);
    }

    // ln1 + bf16 hi/lo split, in place over X1
    prep_x1_kernel<<<16384, 256, 0, stream>>>(X1, ln1g, ln1b);
    const u16* X1p = (const u16*)X1;

    // stages 2+3: one persistent launch (256 chain + 256 worker blocks)
    persist_kernel<<<512, 256, 0, stream>>>(
        G2[0], G2[1], G3[0], G3[1], wh1p, wh2p, hb1, hb2, R[0], R[1],
        (float*)d_out, lastidx, bng, bnb,
        X1p, w1p, b1, ln2g, ln2b, w2p, b2, fl);
}